// Round 1
// baseline (303.133 us; speedup 1.0000x reference)
//
#include <hip/hip_runtime.h>
#include <math.h>

// Dims
#define IMG 64
#define NSLICE 16
#define NCOIL 4
#define NSING 4
#define NECHO 3
#define NRO 32
#define NPT 96
#define NEC (NECHO*NCOIL)     // 12 channels after ur-contraction
#define NPIX (IMG*IMG)        // 4096

// ---------------------------------------------------------------------------
// Kernel A: per-pixel. Stage singulars+smap in LDS, z-DFT (16 bins), contract
// ur per readout -> img_w[r][ec][x*64+y]  (ec = e*4 + c), complex float2.
// ---------------------------------------------------------------------------
__global__ __launch_bounds__(256) void precompute_imgw(
    const float2* __restrict__ sing,   // [4096][16][4][3] complex: ((px*16+z)*4+n)*3+e
    const float2* __restrict__ smap,   // [4][4096][16] complex
    const float*  __restrict__ ur,     // [32][4]
    const int*    __restrict__ zb,     // [32]
    float2* __restrict__ imgw)         // [32][12][4096]
{
  __shared__ float2 sc_sh[192];   // [z][n*3+e] = z*12 + s
  __shared__ float2 sm_sh[64];    // [c][z]
  __shared__ float2 wt_sh[256];   // [kz][z]
  __shared__ float2 b_sh[768];    // [(s*4+c)*16 + z]
  __shared__ float2 f_sh[768];    // [(s*4+c)*16 + kz]
  __shared__ float  ur_sh[128];
  __shared__ int    zb_sh[32];

  const int px = blockIdx.x;
  const int t  = threadIdx.x;

  if (t < 192) sc_sh[t] = sing[px*192 + t];          // t = z*12 + s (n*3+e)
  if (t < 64) {
    int c = t >> 4, z = t & 15;
    sm_sh[t] = smap[c*65536 + px*16 + z];
  }
  {
    int kz = t >> 4, z = t & 15;
    int m = (kz * z) & 15;
    float s, cc;
    __sincosf(-0.39269908169872414f * (float)m, &s, &cc); // -2*pi/16 * m
    wt_sh[t] = make_float2(cc, s);
  }
  if (t < 128) ur_sh[t] = ur[t];
  if (t < 32)  zb_sh[t] = zb[t];
  __syncthreads();

  // b[s][c][z] = sign(z) * sc[s,z] * sm[c,z]
  for (int i = t; i < 768; i += 256) {
    int s = i >> 6, c = (i >> 4) & 3, z = i & 15;
    float2 a = sc_sh[z*12 + s];
    float2 m = sm_sh[c*16 + z];
    float sgn = (z & 1) ? -1.f : 1.f;
    b_sh[i] = make_float2(sgn * (a.x*m.x - a.y*m.y),
                          sgn * (a.x*m.y + a.y*m.x));
  }
  __syncthreads();

  // f[s][c][kz] = sum_z b[s][c][z] * W[kz][z]
  for (int i = t; i < 768; i += 256) {
    int kz = i & 15;
    int base = i & ~15;
    float fr = 0.f, fi = 0.f;
    #pragma unroll
    for (int z = 0; z < 16; ++z) {
      float2 b = b_sh[base + z];
      float2 w = wt_sh[kz*16 + z];
      fr = fmaf(b.x, w.x, fr); fr = fmaf(-b.y, w.y, fr);
      fi = fmaf(b.x, w.y, fi); fi = fmaf(b.y, w.x, fi);
    }
    f_sh[i] = make_float2(fr, fi);
  }
  __syncthreads();

  // img_w[r][ec] = sum_n ur[r,n] * f[(n*3+e)][c][zb[r]]
  for (int i = t; i < 384; i += 256) {
    int r = i / 12, ec = i % 12;
    int e = ec >> 2, c = ec & 3;
    int kz = zb_sh[r];
    float vr = 0.f, vi = 0.f;
    #pragma unroll
    for (int n = 0; n < 4; ++n) {
      float u = ur_sh[r*4 + n];
      float2 f = f_sh[((n*3 + e)*4 + c)*16 + kz];
      vr = fmaf(u, f.x, vr);
      vi = fmaf(u, f.y, vi);
    }
    imgw[(r*12 + ec)*4096 + px] = make_float2(vr, vi);
  }
}

// ---------------------------------------------------------------------------
// Kernel B: main NUFFT. 1 wave per block; lane = y; img_w column in registers.
// grid = 32r * 12ec * 8 p-splits = 3072 blocks of 64 threads.
// out[p][c][r][e] complex.
// ---------------------------------------------------------------------------
#define PSPLIT 8
#define PPB (NPT/PSPLIT)   // 12 points per block

__global__ __launch_bounds__(64, 3) void nufft_points(
    const float*  __restrict__ ktraj,  // [32][96][2]
    const float2* __restrict__ imgw,   // [32][12][4096]
    float2* __restrict__ out)          // [96][4][32][3] complex
{
  __shared__ float2 ex_sh[PPB * 64];   // [pp][x]

  const int bid = blockIdx.x;
  const int r   = bid & 31;
  const int ec  = (bid >> 5) % 12;
  const int ps  = bid / (32 * 12);
  const int p0  = ps * PPB;
  const int e   = ec >> 2;
  const int c   = ec & 3;
  const int t   = threadIdx.x;   // lane = y = x-phase index

  // Phase 1: ex[pp][x] = exp(-i * w0 * (x-32)) for this block's 12 points.
  #pragma unroll
  for (int k = 0; k < PPB; ++k) {
    float w0 = ktraj[(r*96 + p0 + k) * 2];
    float ang = -w0 * (float)(t - 32);
    float s, cc;
    __sincosf(ang, &s, &cc);
    ex_sh[k*64 + t] = make_float2(cc, s);
  }

  // Phase 2: load img_w[r][ec][x][y=lane] column into registers (coalesced).
  const float2* wbase = imgw + (r*12 + ec) * 4096;
  float2 w[64];
  #pragma unroll
  for (int x = 0; x < 64; ++x) w[x] = wbase[x*64 + t];

  __syncthreads();

  const float yy = (float)(t - 32);

  for (int pp = 0; pp < PPB; ++pp) {
    const int p = p0 + pp;
    float w1 = ktraj[(r*96 + p)*2 + 1];
    float es, ecs;
    __sincosf(-w1 * yy, &es, &ecs);          // ey = (ecs, es)

    float2 acc = make_float2(0.f, 0.f);
    #pragma unroll
    for (int x = 0; x < 64; ++x) {
      float2 ex = ex_sh[pp*64 + x];          // lane-uniform broadcast
      // acc += w[x] * ex   (complex), written pk-fma friendly:
      acc.x = fmaf(w[x].x, ex.x, acc.x);
      acc.y = fmaf(w[x].x, ex.y, acc.y);
      acc.x = fmaf(w[x].y, -ex.y, acc.x);
      acc.y = fmaf(w[x].y, ex.x, acc.y);
    }
    // multiply by ey, then reduce over y (= lanes)
    float vr = acc.x * ecs - acc.y * es;
    float vi = acc.x * es  + acc.y * ecs;
    #pragma unroll
    for (int off = 32; off; off >>= 1) {
      vr += __shfl_xor(vr, off);
      vi += __shfl_xor(vi, off);
    }
    if (t == 0) {
      out[((p*4 + c)*32 + r)*3 + e] = make_float2(vr, vi);
    }
  }
}

// ---------------------------------------------------------------------------
extern "C" void kernel_launch(void* const* d_in, const int* in_sizes, int n_in,
                              void* d_out, int out_size, void* d_ws, size_t ws_size,
                              hipStream_t stream) {
  const float2* sing  = (const float2*)d_in[0];
  const float2* smap  = (const float2*)d_in[1];
  const float*  ktraj = (const float*)d_in[2];
  const float*  ur    = (const float*)d_in[3];
  const int*    zb    = (const int*)d_in[4];
  // d_in[5] = dc, unused by the forward reference.

  float2* imgw = (float2*)d_ws;            // 32*12*4096*8B = 12.58 MB
  float2* out  = (float2*)d_out;

  precompute_imgw<<<NPIX, 256, 0, stream>>>(sing, smap, ur, zb, imgw);
  nufft_points<<<NRO * NEC * PSPLIT, 64, 0, stream>>>(ktraj, imgw, out);
}

// Round 2
// 133.037 us; speedup vs baseline: 2.2786x; 2.2786x over previous
//
#include <hip/hip_runtime.h>
#include <math.h>

// Dims
#define IMG 64
#define NPIX 4096      // 64*64 pixels, px = ix*64 + iy
#define NSLICE 16
#define NCOIL 4
#define NSING 4
#define NECHO 3
#define NRO 32
#define NPT 96
#define NEC 12         // NECHO*NCOIL after ur-contraction

// ws layout: ex table [32r][64x][96p] float2 (1.57 MB), then imgw [32r][12ec][4096px] float2 (12.6 MB)
#define EXG_F2 (NRO * IMG * NPT)          // 196608 float2

// ---------------------------------------------------------------------------
// Kernel A2: phase table ex[r][x][p] = exp(-i * w0(r,p) * (x-32))
// ---------------------------------------------------------------------------
__global__ __launch_bounds__(256) void build_ex(
    const float* __restrict__ kt,    // [32][96][2]
    float2* __restrict__ exg)        // [32][64][96]
{
  int g = blockIdx.x * 256 + threadIdx.x;     // 0 .. 196607 exactly
  int p = g % 96;
  int x = (g / 96) & 63;
  int r = g / (96 * 64);
  float w0 = kt[(r * 96 + p) * 2];
  float s, c;
  __sincosf(-w0 * (float)(x - 32), &s, &c);
  exg[g] = make_float2(c, s);
}

// ---------------------------------------------------------------------------
// Kernel A: imgw[r][ec][px] = sum_n ur[r,n] * DFTz(sign * sc * sm)[n,e,c, zb[r]]
// Block = 256 threads = 4 px * 64 lanes. Lane (s,c) holds b[z] in regs and
// does a radix-2 DFT-16 entirely in registers (twiddles are literals).
// ---------------------------------------------------------------------------
__global__ __launch_bounds__(256) void precompute_imgw(
    const float2* __restrict__ sing,   // [4096px][16z][4n][3e]
    const float2* __restrict__ smap,   // [4c][4096px][16z]
    const float*  __restrict__ ur,     // [32][4]
    const int*    __restrict__ zb,     // [32]
    float2* __restrict__ imgw)         // [32][12][4096]
{
  __shared__ float2 sc_sh[4 * 192];    // [pxl][z*12 + s]
  __shared__ float2 sm_sh[4 * 64];     // [pxl][c*16 + z]
  __shared__ float2 f_sh[4 * 48 * 16]; // [pxl][s*4+c][kz]   24 KB
  __shared__ float  ur_sh[128];
  __shared__ int    zb_sh[32];

  const int t   = threadIdx.x;
  const int px0 = blockIdx.x * 4;

  // stage inputs (coalesced)
  for (int j = t; j < 768; j += 256) sc_sh[j] = sing[px0 * 192 + j];
  {
    int c = t >> 6, pxl = (t >> 4) & 3, z = t & 15;
    sm_sh[pxl * 64 + c * 16 + z] = smap[c * 65536 + (px0 + pxl) * 16 + z];
  }
  if (t < 128) ur_sh[t] = ur[t];
  if (t < 32)  zb_sh[t] = zb[t];
  __syncthreads();

  const int pxl = t >> 6, lane = t & 63;
  const int s = lane >> 2, c = lane & 3;

  // W16[m] = exp(-2*pi*i*m/16)
  const float wr[16] = { 1.f,  0.92387953f,  0.70710678f,  0.38268343f,
                         0.f, -0.38268343f, -0.70710678f, -0.92387953f,
                        -1.f, -0.92387953f, -0.70710678f, -0.38268343f,
                         0.f,  0.38268343f,  0.70710678f,  0.92387953f };
  const float wi[16] = { 0.f, -0.38268343f, -0.70710678f, -0.92387953f,
                        -1.f, -0.92387953f, -0.70710678f, -0.38268343f,
                         0.f,  0.38268343f,  0.70710678f,  0.92387953f,
                         1.f,  0.92387953f,  0.70710678f,  0.38268343f };

  if (lane < 48) {
    float br[16], bi[16];
    #pragma unroll
    for (int z = 0; z < 16; ++z) {
      float2 a = sc_sh[pxl * 192 + z * 12 + s];
      float2 m = sm_sh[pxl * 64 + c * 16 + z];
      float sg = (z & 1) ? -1.f : 1.f;
      br[z] = sg * (a.x * m.x - a.y * m.y);
      bi[z] = sg * (a.x * m.y + a.y * m.x);
    }
    // f[kz] = E[kz&7] +/- W16[kz&7]*O[kz&7];  E/O = DFT8 of even/odd z
    float Er[8], Ei[8], Or[8], Oi[8];
    #pragma unroll
    for (int k = 0; k < 8; ++k) {
      float er = 0.f, ei = 0.f, pr = 0.f, pi = 0.f;
      #pragma unroll
      for (int m = 0; m < 8; ++m) {
        const int idx = (2 * k * m) & 15;
        er = fmaf(br[2*m],    wr[idx], er); er = fmaf(-bi[2*m],   wi[idx], er);
        ei = fmaf(br[2*m],    wi[idx], ei); ei = fmaf( bi[2*m],   wr[idx], ei);
        pr = fmaf(br[2*m+1],  wr[idx], pr); pr = fmaf(-bi[2*m+1], wi[idx], pr);
        pi = fmaf(br[2*m+1],  wi[idx], pi); pi = fmaf( bi[2*m+1], wr[idx], pi);
      }
      Er[k] = er; Ei[k] = ei; Or[k] = pr; Oi[k] = pi;
    }
    float2* frow = &f_sh[(pxl * 48 + s * 4 + c) * 16];
    #pragma unroll
    for (int k = 0; k < 8; ++k) {
      float tr = Or[k] * wr[k] - Oi[k] * wi[k];
      float ti = Or[k] * wi[k] + Oi[k] * wr[k];
      frow[k]     = make_float2(Er[k] + tr, Ei[k] + ti);
      frow[k + 8] = make_float2(Er[k] - tr, Ei[k] - ti);
    }
  }
  __syncthreads();

  // contraction + store: 1536 outputs (4 px * 384 rc), 6 per thread
  for (int j = t; j < 1536; j += 256) {
    int rc  = j >> 2;       // r*12 + ec
    int pl  = j & 3;
    int r   = rc / 12, ec = rc - r * 12;
    int e   = ec >> 2, cc = ec & 3;
    int kz  = zb_sh[r];
    float vr = 0.f, vi = 0.f;
    #pragma unroll
    for (int n = 0; n < 4; ++n) {
      float u  = ur_sh[r * 4 + n];
      float2 f = f_sh[(pl * 48 + (n * 3 + e) * 4 + cc) * 16 + kz];
      vr = fmaf(u, f.x, vr);
      vi = fmaf(u, f.y, vi);
    }
    imgw[rc * 4096 + px0 + pl] = make_float2(vr, vi);
  }
}

// ---------------------------------------------------------------------------
// Kernel B: one block (512 thr = 8 waves) per (r,ec). imgw column staged once
// in LDS; wave wv owns 12 points; lane = y. Inner loop: 1 ds_read_b64 +
// 12 uniform 8B loads + 48 fmaf per x. Accumulators: 24 VGPRs.
// ---------------------------------------------------------------------------
__global__ __launch_bounds__(512, 4) void nufft_points(
    const float*  __restrict__ kt,     // [32][96][2]
    const float2* __restrict__ exg,    // [32][64][96]
    const float2* __restrict__ imgw,   // [32][12][4096]
    float2* __restrict__ out)          // [96][4][32][3]
{
  __shared__ float2 w_sh[4096];        // 32 KB

  const int bid = blockIdx.x;          // 384 = 32r * 12ec
  const int r   = bid & 31;
  const int ec  = bid >> 5;
  const int e   = ec >> 2, c = ec & 3;
  const int t    = threadIdx.x;
  const int wv   = t >> 6;
  const int lane = t & 63;
  const int p0   = wv * 12;

  // stage imgw column (32 KB, coalesced float4)
  {
    const float4* wsrc = (const float4*)(imgw + (r * 12 + ec) * 4096);
    float4* wdst = (float4*)w_sh;
    #pragma unroll
    for (int j = 0; j < 4; ++j) wdst[t + j * 512] = wsrc[t + j * 512];
  }
  __syncthreads();

  float accr[12], acci[12];
  #pragma unroll
  for (int pp = 0; pp < 12; ++pp) { accr[pp] = 0.f; acci[pp] = 0.f; }

  #pragma unroll 2
  for (int x = 0; x < 64; ++x) {
    float2 w = w_sh[x * 64 + lane];
    const float* exb = (const float*)(exg + (r * 64 + x) * 96 + p0);
    #pragma unroll
    for (int pp = 0; pp < 12; ++pp) {
      float er = exb[2 * pp];
      float ei = exb[2 * pp + 1];
      accr[pp] = fmaf(w.x, er, accr[pp]);
      accr[pp] = fmaf(-w.y, ei, accr[pp]);
      acci[pp] = fmaf(w.x, ei, acci[pp]);
      acci[pp] = fmaf(w.y, er, acci[pp]);
    }
  }

  // epilogue: * ey(p, lane), reduce over lanes, store
  const float yy = (float)(lane - 32);
  #pragma unroll
  for (int pp = 0; pp < 12; ++pp) {
    const int p = p0 + pp;
    float w1 = kt[(r * 96 + p) * 2 + 1];
    float es, ecos;
    __sincosf(-w1 * yy, &es, &ecos);
    float vr = accr[pp] * ecos - acci[pp] * es;
    float vi = accr[pp] * es + acci[pp] * ecos;
    #pragma unroll
    for (int off = 32; off; off >>= 1) {
      vr += __shfl_xor(vr, off);
      vi += __shfl_xor(vi, off);
    }
    if (lane == 0) out[((p * 4 + c) * 32 + r) * 3 + e] = make_float2(vr, vi);
  }
}

// ---------------------------------------------------------------------------
extern "C" void kernel_launch(void* const* d_in, const int* in_sizes, int n_in,
                              void* d_out, int out_size, void* d_ws, size_t ws_size,
                              hipStream_t stream) {
  const float2* sing  = (const float2*)d_in[0];
  const float2* smap  = (const float2*)d_in[1];
  const float*  ktraj = (const float*)d_in[2];
  const float*  ur    = (const float*)d_in[3];
  const int*    zbin  = (const int*)d_in[4];
  // d_in[5] = dc, unused in forward

  float2* exg  = (float2*)d_ws;          // 1.57 MB
  float2* imgw = exg + EXG_F2;           // 12.6 MB
  float2* out  = (float2*)d_out;

  build_ex<<<EXG_F2 / 256, 256, 0, stream>>>(ktraj, exg);
  precompute_imgw<<<NPIX / 4, 256, 0, stream>>>(sing, smap, ur, zbin, imgw);
  nufft_points<<<NRO * NEC, 512, 0, stream>>>(ktraj, exg, imgw, out);
}

// Round 3
// 102.205 us; speedup vs baseline: 2.9659x; 1.3017x over previous
//
#include <hip/hip_runtime.h>
#include <math.h>

// Dims
#define IMG 64
#define NPIX 4096      // 64*64 pixels, px = ix*64 + iy
#define NSLICE 16
#define NCOIL 4
#define NSING 4
#define NECHO 3
#define NRO 32
#define NPT 96
#define NEC 12         // NECHO*NCOIL after ur-contraction

typedef float v2f __attribute__((ext_vector_type(2)));

// ws layout: ex table [32r][64x][96p] float2 (1.57 MB), then imgw [32r][12ec][4096px] float2 (12.6 MB)
#define EXG_F2 (NRO * IMG * NPT)          // 196608 float2

// ---------------------------------------------------------------------------
// Kernel A2: phase table ex[r][x][p] = exp(-i * w0(r,p) * (x-32))
// ---------------------------------------------------------------------------
__global__ __launch_bounds__(256) void build_ex(
    const float* __restrict__ kt,    // [32][96][2]
    float2* __restrict__ exg)        // [32][64][96]
{
  int g = blockIdx.x * 256 + threadIdx.x;     // 0 .. 196607 exactly
  int p = g % 96;
  int x = (g / 96) & 63;
  int r = g / (96 * 64);
  float w0 = kt[(r * 96 + p) * 2];
  float s, c;
  __sincosf(-w0 * (float)(x - 32), &s, &c);
  exg[g] = make_float2(c, s);
}

// ---------------------------------------------------------------------------
// Kernel A: imgw[r][ec][px] = sum_n ur[r,n] * DFTz(sign * sc * sm)[n,e,c, zb[r]]
// Block = 256 threads = 4 px * 64 lanes. Lane (s,c) holds b[z] in regs and
// does a radix-2 DFT-16 entirely in registers (twiddles are literals).
// ---------------------------------------------------------------------------
__global__ __launch_bounds__(256) void precompute_imgw(
    const float2* __restrict__ sing,   // [4096px][16z][4n][3e]
    const float2* __restrict__ smap,   // [4c][4096px][16z]
    const float*  __restrict__ ur,     // [32][4]
    const int*    __restrict__ zb,     // [32]
    float2* __restrict__ imgw)         // [32][12][4096]
{
  __shared__ float2 sc_sh[4 * 192];    // [pxl][z*12 + s]
  __shared__ float2 sm_sh[4 * 64];     // [pxl][c*16 + z]
  __shared__ float2 f_sh[4 * 48 * 16]; // [pxl][s*4+c][kz]   24 KB
  __shared__ float  ur_sh[128];
  __shared__ int    zb_sh[32];

  const int t   = threadIdx.x;
  const int px0 = blockIdx.x * 4;

  // stage inputs (coalesced)
  for (int j = t; j < 768; j += 256) sc_sh[j] = sing[px0 * 192 + j];
  {
    int c = t >> 6, pxl = (t >> 4) & 3, z = t & 15;
    sm_sh[pxl * 64 + c * 16 + z] = smap[c * 65536 + (px0 + pxl) * 16 + z];
  }
  if (t < 128) ur_sh[t] = ur[t];
  if (t < 32)  zb_sh[t] = zb[t];
  __syncthreads();

  const int pxl = t >> 6, lane = t & 63;
  const int s = lane >> 2, c = lane & 3;

  // W16[m] = exp(-2*pi*i*m/16)
  const float wr[16] = { 1.f,  0.92387953f,  0.70710678f,  0.38268343f,
                         0.f, -0.38268343f, -0.70710678f, -0.92387953f,
                        -1.f, -0.92387953f, -0.70710678f, -0.38268343f,
                         0.f,  0.38268343f,  0.70710678f,  0.92387953f };
  const float wi[16] = { 0.f, -0.38268343f, -0.70710678f, -0.92387953f,
                        -1.f, -0.92387953f, -0.70710678f, -0.38268343f,
                         0.f,  0.38268343f,  0.70710678f,  0.92387953f,
                         1.f,  0.92387953f,  0.70710678f,  0.38268343f };

  if (lane < 48) {
    float br[16], bi[16];
    #pragma unroll
    for (int z = 0; z < 16; ++z) {
      float2 a = sc_sh[pxl * 192 + z * 12 + s];
      float2 m = sm_sh[pxl * 64 + c * 16 + z];
      float sg = (z & 1) ? -1.f : 1.f;
      br[z] = sg * (a.x * m.x - a.y * m.y);
      bi[z] = sg * (a.x * m.y + a.y * m.x);
    }
    // f[kz] = E[kz&7] +/- W16[kz&7]*O[kz&7];  E/O = DFT8 of even/odd z
    float Er[8], Ei[8], Or[8], Oi[8];
    #pragma unroll
    for (int k = 0; k < 8; ++k) {
      float er = 0.f, ei = 0.f, pr = 0.f, pi = 0.f;
      #pragma unroll
      for (int m = 0; m < 8; ++m) {
        const int idx = (2 * k * m) & 15;
        er = fmaf(br[2*m],    wr[idx], er); er = fmaf(-bi[2*m],   wi[idx], er);
        ei = fmaf(br[2*m],    wi[idx], ei); ei = fmaf( bi[2*m],   wr[idx], ei);
        pr = fmaf(br[2*m+1],  wr[idx], pr); pr = fmaf(-bi[2*m+1], wi[idx], pr);
        pi = fmaf(br[2*m+1],  wi[idx], pi); pi = fmaf( bi[2*m+1], wr[idx], pi);
      }
      Er[k] = er; Ei[k] = ei; Or[k] = pr; Oi[k] = pi;
    }
    float2* frow = &f_sh[(pxl * 48 + s * 4 + c) * 16];
    #pragma unroll
    for (int k = 0; k < 8; ++k) {
      float tr = Or[k] * wr[k] - Oi[k] * wi[k];
      float ti = Or[k] * wi[k] + Oi[k] * wr[k];
      frow[k]     = make_float2(Er[k] + tr, Ei[k] + ti);
      frow[k + 8] = make_float2(Er[k] - tr, Ei[k] - ti);
    }
  }
  __syncthreads();

  // contraction + store: 1536 outputs (4 px * 384 rc), 6 per thread
  for (int j = t; j < 1536; j += 256) {
    int rc  = j >> 2;       // r*12 + ec
    int pl  = j & 3;
    int r   = rc / 12, ec = rc - r * 12;
    int e   = ec >> 2, cc = ec & 3;
    int kz  = zb_sh[r];
    float vr = 0.f, vi = 0.f;
    #pragma unroll
    for (int n = 0; n < 4; ++n) {
      float u  = ur_sh[r * 4 + n];
      float2 f = f_sh[(pl * 48 + (n * 3 + e) * 4 + cc) * 16 + kz];
      vr = fmaf(u, f.x, vr);
      vi = fmaf(u, f.y, vi);
    }
    imgw[rc * 4096 + px0 + pl] = make_float2(vr, vi);
  }
}

// ---------------------------------------------------------------------------
// Kernel B: one block (256 thr = 4 waves) per (r,ec,ps). imgw column staged
// once in LDS; wave wv owns 12 points; lane = y.
//
// Inner loop tricks:
//  * p0 via readfirstlane -> ex pointer provably wave-uniform -> s_load on
//    the scalar pipe (no vmcnt stall in the VALU stream).
//  * complex MAC split into two LINEAR packed accumulators:
//      accA[pp] += w.x * (er,ei);  accB[pp] += w.y * (er,ei)
//    recombined after the loop: re = accA.x - accB.y, im = accA.y + accB.x.
//    -> one v_pk_fma_f32 each (24 packed FMA / x instead of 48 scalar).
// ---------------------------------------------------------------------------
__global__ __launch_bounds__(256, 3) void nufft_points(
    const float*  __restrict__ kt,     // [32][96][2]
    const float2* __restrict__ exg,    // [32][64][96]
    const float2* __restrict__ imgw,   // [32][12][4096]
    float2* __restrict__ out)          // [96][4][32][3]
{
  __shared__ float2 w_sh[4096];        // 32 KB

  const int bid = blockIdx.x;          // 768 = 32r * 12ec * 2ps
  const int r   = bid & 31;
  const int ec  = (bid >> 5) % 12;
  const int ps  = bid / 384;
  const int e   = ec >> 2, c = ec & 3;
  const int t    = threadIdx.x;
  const int lane = t & 63;
  // wave-uniform starting point index (forces scalar ex loads)
  const int p0 = __builtin_amdgcn_readfirstlane(ps * 48 + (t >> 6) * 12);

  // stage imgw column (32 KB, coalesced float4)
  {
    const float4* wsrc = (const float4*)(imgw + (r * 12 + ec) * 4096);
    float4* wdst = (float4*)w_sh;
    #pragma unroll
    for (int j = 0; j < 8; ++j) wdst[t + j * 256] = wsrc[t + j * 256];
  }
  __syncthreads();

  v2f accA[12], accB[12];
  #pragma unroll
  for (int pp = 0; pp < 12; ++pp) { accA[pp] = (v2f)(0.f); accB[pp] = (v2f)(0.f); }

  const v2f* __restrict__ exgv = (const v2f*)exg;

  #pragma unroll 4
  for (int x = 0; x < 64; ++x) {
    float2 w = w_sh[x * 64 + lane];
    const v2f* exb = exgv + ((r * 64 + x) * 96 + p0);   // wave-uniform addr
    #pragma unroll
    for (int pp = 0; pp < 12; ++pp) {
      v2f ev = exb[pp];
      v2f wx = { w.x, w.x };
      v2f wy = { w.y, w.y };
      accA[pp] = __builtin_elementwise_fma(wx, ev, accA[pp]);
      accB[pp] = __builtin_elementwise_fma(wy, ev, accB[pp]);
    }
  }

  // epilogue: recombine, * ey(p, lane), reduce over lanes, store
  const float yy = (float)(lane - 32);
  #pragma unroll
  for (int pp = 0; pp < 12; ++pp) {
    const int p = p0 + pp;
    float w1 = kt[(r * 96 + p) * 2 + 1];
    float es, ecos;
    __sincosf(-w1 * yy, &es, &ecos);
    float vr0 = accA[pp].x - accB[pp].y;
    float vi0 = accA[pp].y + accB[pp].x;
    float vr = vr0 * ecos - vi0 * es;
    float vi = vr0 * es + vi0 * ecos;
    #pragma unroll
    for (int off = 32; off; off >>= 1) {
      vr += __shfl_xor(vr, off);
      vi += __shfl_xor(vi, off);
    }
    if (lane == 0) out[((p * 4 + c) * 32 + r) * 3 + e] = make_float2(vr, vi);
  }
}

// ---------------------------------------------------------------------------
extern "C" void kernel_launch(void* const* d_in, const int* in_sizes, int n_in,
                              void* d_out, int out_size, void* d_ws, size_t ws_size,
                              hipStream_t stream) {
  const float2* sing  = (const float2*)d_in[0];
  const float2* smap  = (const float2*)d_in[1];
  const float*  ktraj = (const float*)d_in[2];
  const float*  ur    = (const float*)d_in[3];
  const int*    zbin  = (const int*)d_in[4];
  // d_in[5] = dc, unused in forward

  float2* exg  = (float2*)d_ws;          // 1.57 MB
  float2* imgw = exg + EXG_F2;           // 12.6 MB
  float2* out  = (float2*)d_out;

  build_ex<<<EXG_F2 / 256, 256, 0, stream>>>(ktraj, exg);
  precompute_imgw<<<NPIX / 4, 256, 0, stream>>>(sing, smap, ur, zbin, imgw);
  nufft_points<<<NRO * NEC * 2, 256, 0, stream>>>(ktraj, exg, imgw, out);
}

// Round 4
// 99.297 us; speedup vs baseline: 3.0528x; 1.0293x over previous
//
#include <hip/hip_runtime.h>
#include <math.h>

// Dims
#define IMG 64
#define NPIX 4096      // 64*64 pixels, px = ix*64 + iy
#define NSLICE 16
#define NCOIL 4
#define NSING 4
#define NECHO 3
#define NRO 32
#define NPT 96
#define NEC 12         // NECHO*NCOIL after ur-contraction

typedef float v2f __attribute__((ext_vector_type(2)));

// ws layout: ex2 table [32r][33k][96p] float2 (811 KB), then imgw [32r][12ec][4096px] float2 (12.6 MB)
// ex2[r][k][p] = exp(-i*k*w0(r,p)) for k=1..31 ; k=0 slot holds exp(+32i*w0) (the x=0 special)
#define EXG2_F2 (NRO * 33 * NPT)          // 101376 float2

// ---------------------------------------------------------------------------
// Kernel A: imgw[r][ec][px] = sum_n ur[r,n] * DFTz(sign * sc * sm)[n,e,c, zb[r]]
// Block = 256 threads = 4 px * 64 lanes. Lane (s,c) holds b[z] in regs and
// does a radix-2 DFT-16 entirely in registers (twiddles are literals).
// First 396 blocks additionally emit the folded phase table ex2 (1 sincos/thr).
// ---------------------------------------------------------------------------
__global__ __launch_bounds__(256) void precompute_imgw(
    const float2* __restrict__ sing,   // [4096px][16z][4n][3e]
    const float2* __restrict__ smap,   // [4c][4096px][16z]
    const float*  __restrict__ ur,     // [32][4]
    const int*    __restrict__ zb,     // [32]
    const float*  __restrict__ kt,     // [32][96][2]
    float2* __restrict__ ex2,          // [32][33][96]
    float2* __restrict__ imgw)         // [32][12][4096]
{
  __shared__ float2 sc_sh[4 * 192];    // [pxl][z*12 + s]
  __shared__ float2 sm_sh[4 * 64];     // [pxl][c*16 + z]
  __shared__ float2 f_sh[4 * 48 * 16]; // [pxl][s*4+c][kz]   24 KB
  __shared__ float  ur_sh[128];
  __shared__ int    zb_sh[32];

  const int t   = threadIdx.x;
  const int px0 = blockIdx.x * 4;

  // side job: phase table (32*33*96 = 101376 = 396 blocks * 256 threads)
  if (blockIdx.x < 396) {
    int g = blockIdx.x * 256 + t;
    int p = g % 96;
    int k = (g / 96) % 33;
    int r = g / (96 * 33);
    float w0 = kt[(r * 96 + p) * 2];
    float ang = (k == 0) ? (32.0f * w0) : (-(float)k * w0);
    float s_, c_;
    __sincosf(ang, &s_, &c_);
    ex2[g] = make_float2(c_, s_);
  }

  // stage inputs (coalesced)
  for (int j = t; j < 768; j += 256) sc_sh[j] = sing[px0 * 192 + j];
  {
    int c = t >> 6, pxl = (t >> 4) & 3, z = t & 15;
    sm_sh[pxl * 64 + c * 16 + z] = smap[c * 65536 + (px0 + pxl) * 16 + z];
  }
  if (t < 128) ur_sh[t] = ur[t];
  if (t < 32)  zb_sh[t] = zb[t];
  __syncthreads();

  const int pxl = t >> 6, lane = t & 63;
  const int s = lane >> 2, c = lane & 3;

  // W16[m] = exp(-2*pi*i*m/16)
  const float wr[16] = { 1.f,  0.92387953f,  0.70710678f,  0.38268343f,
                         0.f, -0.38268343f, -0.70710678f, -0.92387953f,
                        -1.f, -0.92387953f, -0.70710678f, -0.38268343f,
                         0.f,  0.38268343f,  0.70710678f,  0.92387953f };
  const float wi[16] = { 0.f, -0.38268343f, -0.70710678f, -0.92387953f,
                        -1.f, -0.92387953f, -0.70710678f, -0.38268343f,
                         0.f,  0.38268343f,  0.70710678f,  0.92387953f,
                         1.f,  0.92387953f,  0.70710678f,  0.38268343f };

  if (lane < 48) {
    float br[16], bi[16];
    #pragma unroll
    for (int z = 0; z < 16; ++z) {
      float2 a = sc_sh[pxl * 192 + z * 12 + s];
      float2 m = sm_sh[pxl * 64 + c * 16 + z];
      float sg = (z & 1) ? -1.f : 1.f;
      br[z] = sg * (a.x * m.x - a.y * m.y);
      bi[z] = sg * (a.x * m.y + a.y * m.x);
    }
    // f[kz] = E[kz&7] +/- W16[kz&7]*O[kz&7];  E/O = DFT8 of even/odd z
    float Er[8], Ei[8], Or[8], Oi[8];
    #pragma unroll
    for (int k = 0; k < 8; ++k) {
      float er = 0.f, ei = 0.f, pr = 0.f, pi = 0.f;
      #pragma unroll
      for (int m = 0; m < 8; ++m) {
        const int idx = (2 * k * m) & 15;
        er = fmaf(br[2*m],    wr[idx], er); er = fmaf(-bi[2*m],   wi[idx], er);
        ei = fmaf(br[2*m],    wi[idx], ei); ei = fmaf( bi[2*m],   wr[idx], ei);
        pr = fmaf(br[2*m+1],  wr[idx], pr); pr = fmaf(-bi[2*m+1], wi[idx], pr);
        pi = fmaf(br[2*m+1],  wi[idx], pi); pi = fmaf( bi[2*m+1], wr[idx], pi);
      }
      Er[k] = er; Ei[k] = ei; Or[k] = pr; Oi[k] = pi;
    }
    float2* frow = &f_sh[(pxl * 48 + s * 4 + c) * 16];
    #pragma unroll
    for (int k = 0; k < 8; ++k) {
      float tr = Or[k] * wr[k] - Oi[k] * wi[k];
      float ti = Or[k] * wi[k] + Oi[k] * wr[k];
      frow[k]     = make_float2(Er[k] + tr, Ei[k] + ti);
      frow[k + 8] = make_float2(Er[k] - tr, Ei[k] - ti);
    }
  }
  __syncthreads();

  // contraction + store: 1536 outputs (4 px * 384 rc), 6 per thread
  for (int j = t; j < 1536; j += 256) {
    int rc  = j >> 2;       // r*12 + ec
    int pl  = j & 3;
    int r   = rc / 12, ec = rc - r * 12;
    int e   = ec >> 2, cc = ec & 3;
    int kz  = zb_sh[r];
    float vr = 0.f, vi = 0.f;
    #pragma unroll
    for (int n = 0; n < 4; ++n) {
      float u  = ur_sh[r * 4 + n];
      float2 f = f_sh[(pl * 48 + (n * 3 + e) * 4 + cc) * 16 + kz];
      vr = fmaf(u, f.x, vr);
      vi = fmaf(u, f.y, vi);
    }
    imgw[rc * 4096 + px0 + pl] = make_float2(vr, vi);
  }
}

// ---------------------------------------------------------------------------
// Kernel B: one block (256 thr = 4 waves) per (r,ec,ps). Conjugate-folded
// NUFFT: ex(32+k) = conj(ex(32-k)), so fold x-pairs into
//   s = w[32+k]+w[32-k]  (stored as (s.x,s.y) at row 32+k)
//   d = w[32+k]-w[32-k]  (stored as (-d.y,d.x) at row 32-k)
// and per (k,pp): acc += sxy*er + dyx*ei  -> 8 FLOP per x-PAIR (2x cut).
// x=32 (phase 1) and x=0 (phase e^{+32iw0}, ex2 k=0 slot) seed the accumulator.
// ex loads are wave-uniform (readfirstlane p0) -> scalar pipe.
// ---------------------------------------------------------------------------
__global__ __launch_bounds__(256, 3) void nufft_points(
    const float*  __restrict__ kt,     // [32][96][2]
    const float2* __restrict__ ex2,    // [32][33][96]
    const float2* __restrict__ imgw,   // [32][12][4096]
    float2* __restrict__ out)          // [96][4][32][3]
{
  __shared__ float2 w_sh[4096];        // 32 KB

  const int bid = blockIdx.x;          // 768 = 32r * 12ec * 2ps
  const int r   = bid & 31;
  const int ec  = (bid >> 5) % 12;
  const int ps  = bid / 384;
  const int e   = ec >> 2, c = ec & 3;
  const int t    = threadIdx.x;
  const int lane = t & 63;
  // wave-uniform starting point index (forces scalar ex loads)
  const int p0 = __builtin_amdgcn_readfirstlane(ps * 48 + (t >> 6) * 12);

  // stage imgw column (32 KB, coalesced float4)
  {
    const float4* wsrc = (const float4*)(imgw + (r * 12 + ec) * 4096);
    float4* wdst = (float4*)w_sh;
    #pragma unroll
    for (int j = 0; j < 8; ++j) wdst[t + j * 256] = wsrc[t + j * 256];
  }
  __syncthreads();

  // conjugate fold, in place. Rows 0 and 32 stay untouched (k = 1..31).
  float2 wa[8], wb[8];
  #pragma unroll
  for (int j = 0; j < 8; ++j) {
    int idx = t + j * 256;             // 0..2047, active < 1984 = 31*64
    if (idx < 1984) {
      int k = 1 + (idx >> 6), y = idx & 63;
      wa[j] = w_sh[(32 + k) * 64 + y];
      wb[j] = w_sh[(32 - k) * 64 + y];
    }
  }
  __syncthreads();
  #pragma unroll
  for (int j = 0; j < 8; ++j) {
    int idx = t + j * 256;
    if (idx < 1984) {
      int k = 1 + (idx >> 6), y = idx & 63;
      w_sh[(32 + k) * 64 + y] = make_float2(wa[j].x + wb[j].x, wa[j].y + wb[j].y);
      w_sh[(32 - k) * 64 + y] = make_float2(-(wa[j].y - wb[j].y), wa[j].x - wb[j].x);
    }
  }
  __syncthreads();

  const float* __restrict__ exb = (const float*)(ex2 + r * 33 * 96);

  // seed: acc[pp] = w[32] + w[0] * e^{+32i w0(p)}
  v2f acc[12];
  {
    float2 w0v = w_sh[lane];
    float2 w32 = w_sh[32 * 64 + lane];
    #pragma unroll
    for (int pp = 0; pp < 12; ++pp) {
      float er = exb[2 * (p0 + pp)];
      float ei = exb[2 * (p0 + pp) + 1];
      acc[pp].x = w32.x + w0v.x * er - w0v.y * ei;
      acc[pp].y = w32.y + w0v.x * ei + w0v.y * er;
    }
  }

  #pragma unroll 2
  for (int k = 1; k < 32; ++k) {
    v2f sxy = *(const v2f*)&w_sh[(32 + k) * 64 + lane];
    v2f dyx = *(const v2f*)&w_sh[(32 - k) * 64 + lane];
    const float* ekb = exb + k * 192 + 2 * p0;   // wave-uniform
    #pragma unroll
    for (int pp = 0; pp < 12; ++pp) {
      float er = ekb[2 * pp];
      float ei = ekb[2 * pp + 1];
      acc[pp] = __builtin_elementwise_fma(sxy, (v2f)(er), acc[pp]);
      acc[pp] = __builtin_elementwise_fma(dyx, (v2f)(ei), acc[pp]);
    }
  }

  // epilogue: * ey(p, lane), reduce over lanes, store
  const float yy = (float)(lane - 32);
  #pragma unroll
  for (int pp = 0; pp < 12; ++pp) {
    const int p = p0 + pp;
    float w1 = kt[(r * 96 + p) * 2 + 1];
    float es, ecos;
    __sincosf(-w1 * yy, &es, &ecos);
    float vr = acc[pp].x * ecos - acc[pp].y * es;
    float vi = acc[pp].x * es  + acc[pp].y * ecos;
    #pragma unroll
    for (int off = 32; off; off >>= 1) {
      vr += __shfl_xor(vr, off);
      vi += __shfl_xor(vi, off);
    }
    if (lane == 0) out[((p * 4 + c) * 32 + r) * 3 + e] = make_float2(vr, vi);
  }
}

// ---------------------------------------------------------------------------
extern "C" void kernel_launch(void* const* d_in, const int* in_sizes, int n_in,
                              void* d_out, int out_size, void* d_ws, size_t ws_size,
                              hipStream_t stream) {
  const float2* sing  = (const float2*)d_in[0];
  const float2* smap  = (const float2*)d_in[1];
  const float*  ktraj = (const float*)d_in[2];
  const float*  ur    = (const float*)d_in[3];
  const int*    zbin  = (const int*)d_in[4];
  // d_in[5] = dc, unused in forward

  float2* ex2  = (float2*)d_ws;          // 811 KB
  float2* imgw = ex2 + EXG2_F2;          // 12.6 MB
  float2* out  = (float2*)d_out;

  precompute_imgw<<<NPIX / 4, 256, 0, stream>>>(sing, smap, ur, zbin, ktraj, ex2, imgw);
  nufft_points<<<NRO * NEC * 2, 256, 0, stream>>>(ktraj, ex2, imgw, out);
}

// Round 5
// 98.587 us; speedup vs baseline: 3.0748x; 1.0072x over previous
//
#include <hip/hip_runtime.h>
#include <math.h>

// Dims
#define IMG 64
#define NPIX 4096      // 64*64 pixels, px = ix*64 + iy
#define NSLICE 16
#define NCOIL 4
#define NSING 4
#define NECHO 3
#define NRO 32
#define NPT 96
#define NEC 12         // NECHO*NCOIL after ur-contraction

typedef float v2f __attribute__((ext_vector_type(2)));

// ws layout: ex2 table [32r][33k][96p] float2 (811 KB), then imgw [32r][12ec][4096px] float2 (12.6 MB)
// ex2[r][k][p] = exp(-i*k*w0(r,p)) for k=1..31 ; k=0 slot holds exp(+32i*w0) (the x=0 special)
#define EXG2_F2 (NRO * 33 * NPT)          // 101376 float2

// ---------------------------------------------------------------------------
// Kernel A: imgw[r][ec][px] = sum_n ur[r,n] * DFTz(sign * sc * sm)[n,e,c, zb[r]]
// Block = 256 threads = 4 px * 64 lanes. Lane (s,c) holds b[z] in regs and
// does a radix-2 DFT-16 entirely in registers (twiddles are literals).
// First 396 blocks additionally emit the folded phase table ex2 (1 sincos/thr).
// ---------------------------------------------------------------------------
__global__ __launch_bounds__(256) void precompute_imgw(
    const float2* __restrict__ sing,   // [4096px][16z][4n][3e]
    const float2* __restrict__ smap,   // [4c][4096px][16z]
    const float*  __restrict__ ur,     // [32][4]
    const int*    __restrict__ zb,     // [32]
    const float*  __restrict__ kt,     // [32][96][2]
    float2* __restrict__ ex2,          // [32][33][96]
    float2* __restrict__ imgw)         // [32][12][4096]
{
  __shared__ float2 sc_sh[4 * 192];    // [pxl][z*12 + s]
  __shared__ float2 sm_sh[4 * 64];     // [pxl][c*16 + z]
  __shared__ float2 f_sh[4 * 48 * 16]; // [pxl][s*4+c][kz]   24 KB
  __shared__ float  ur_sh[128];
  __shared__ int    zb_sh[32];

  const int t   = threadIdx.x;
  const int px0 = blockIdx.x * 4;

  // side job: phase table (32*33*96 = 101376 = 396 blocks * 256 threads)
  if (blockIdx.x < 396) {
    int g = blockIdx.x * 256 + t;
    int p = g % 96;
    int k = (g / 96) % 33;
    int r = g / (96 * 33);
    float w0 = kt[(r * 96 + p) * 2];
    float ang = (k == 0) ? (32.0f * w0) : (-(float)k * w0);
    float s_, c_;
    __sincosf(ang, &s_, &c_);
    ex2[g] = make_float2(c_, s_);
  }

  // stage inputs (coalesced)
  for (int j = t; j < 768; j += 256) sc_sh[j] = sing[px0 * 192 + j];
  {
    int c = t >> 6, pxl = (t >> 4) & 3, z = t & 15;
    sm_sh[pxl * 64 + c * 16 + z] = smap[c * 65536 + (px0 + pxl) * 16 + z];
  }
  if (t < 128) ur_sh[t] = ur[t];
  if (t < 32)  zb_sh[t] = zb[t];
  __syncthreads();

  const int pxl = t >> 6, lane = t & 63;
  const int s = lane >> 2, c = lane & 3;

  // W16[m] = exp(-2*pi*i*m/16)
  const float wr[16] = { 1.f,  0.92387953f,  0.70710678f,  0.38268343f,
                         0.f, -0.38268343f, -0.70710678f, -0.92387953f,
                        -1.f, -0.92387953f, -0.70710678f, -0.38268343f,
                         0.f,  0.38268343f,  0.70710678f,  0.92387953f };
  const float wi[16] = { 0.f, -0.38268343f, -0.70710678f, -0.92387953f,
                        -1.f, -0.92387953f, -0.70710678f, -0.38268343f,
                         0.f,  0.38268343f,  0.70710678f,  0.92387953f,
                         1.f,  0.92387953f,  0.70710678f,  0.92387953f };
  // NOTE: last row restored below (typo guard) — keep exact table:
  const float wi_fix[16] = { 0.f, -0.38268343f, -0.70710678f, -0.92387953f,
                        -1.f, -0.92387953f, -0.70710678f, -0.38268343f,
                         0.f,  0.38268343f,  0.70710678f,  0.92387953f,
                         1.f,  0.92387953f,  0.70710678f,  0.38268343f };

  if (lane < 48) {
    float br[16], bi[16];
    #pragma unroll
    for (int z = 0; z < 16; ++z) {
      float2 a = sc_sh[pxl * 192 + z * 12 + s];
      float2 m = sm_sh[pxl * 64 + c * 16 + z];
      float sg = (z & 1) ? -1.f : 1.f;
      br[z] = sg * (a.x * m.x - a.y * m.y);
      bi[z] = sg * (a.x * m.y + a.y * m.x);
    }
    // f[kz] = E[kz&7] +/- W16[kz&7]*O[kz&7];  E/O = DFT8 of even/odd z
    float Er[8], Ei[8], Or[8], Oi[8];
    #pragma unroll
    for (int k = 0; k < 8; ++k) {
      float er = 0.f, ei = 0.f, pr = 0.f, pi = 0.f;
      #pragma unroll
      for (int m = 0; m < 8; ++m) {
        const int idx = (2 * k * m) & 15;
        er = fmaf(br[2*m],    wr[idx], er); er = fmaf(-bi[2*m],   wi_fix[idx], er);
        ei = fmaf(br[2*m],    wi_fix[idx], ei); ei = fmaf( bi[2*m],   wr[idx], ei);
        pr = fmaf(br[2*m+1],  wr[idx], pr); pr = fmaf(-bi[2*m+1], wi_fix[idx], pr);
        pi = fmaf(br[2*m+1],  wi_fix[idx], pi); pi = fmaf( bi[2*m+1], wr[idx], pi);
      }
      Er[k] = er; Ei[k] = ei; Or[k] = pr; Oi[k] = pi;
    }
    float2* frow = &f_sh[(pxl * 48 + s * 4 + c) * 16];
    #pragma unroll
    for (int k = 0; k < 8; ++k) {
      float tr = Or[k] * wr[k] - Oi[k] * wi_fix[k];
      float ti = Or[k] * wi_fix[k] + Oi[k] * wr[k];
      frow[k]     = make_float2(Er[k] + tr, Ei[k] + ti);
      frow[k + 8] = make_float2(Er[k] - tr, Ei[k] - ti);
    }
  }
  __syncthreads();

  // contraction + store: 1536 outputs (4 px * 384 rc), 6 per thread
  for (int j = t; j < 1536; j += 256) {
    int rc  = j >> 2;       // r*12 + ec
    int pl  = j & 3;
    int r   = rc / 12, ec = rc - r * 12;
    int e   = ec >> 2, cc = ec & 3;
    int kz  = zb_sh[r];
    float vr = 0.f, vi = 0.f;
    #pragma unroll
    for (int n = 0; n < 4; ++n) {
      float u  = ur_sh[r * 4 + n];
      float2 f = f_sh[(pl * 48 + (n * 3 + e) * 4 + cc) * 16 + kz];
      vr = fmaf(u, f.x, vr);
      vi = fmaf(u, f.y, vi);
    }
    imgw[rc * 4096 + px0 + pl] = make_float2(vr, vi);
  }
}

// ---------------------------------------------------------------------------
// Kernel B: one block (256 thr = 4 waves) per (r,ec,ps). Conjugate-folded
// NUFFT. NEW in R5: the ex2 slice (33k x 48p, 12.4 KB) is staged into LDS in
// the prologue -> the K-loop touches ONLY LDS (broadcast ex reads, free
// 2-way-alias w reads) + v_pk_fma. No global loads in the hot loop.
// ---------------------------------------------------------------------------
__global__ __launch_bounds__(256, 3) void nufft_points(
    const float*  __restrict__ kt,     // [32][96][2]
    const float2* __restrict__ ex2,    // [32][33][96]
    const float2* __restrict__ imgw,   // [32][12][4096]
    float2* __restrict__ out)          // [96][4][32][3]
{
  __shared__ float2 w_sh[4096];        // 32 KB
  __shared__ float2 ex_sh[33 * 48];    // 12.4 KB

  const int bid = blockIdx.x;          // 768 = 32r * 12ec * 2ps
  const int r   = bid & 31;
  const int ec  = (bid >> 5) % 12;
  const int ps  = bid / 384;
  const int e   = ec >> 2, c = ec & 3;
  const int t    = threadIdx.x;
  const int lane = t & 63;
  const int p0l  = (t >> 6) * 12;      // local point base (0,12,24,36)
  const int p0   = ps * 48 + p0l;      // global point base

  // stage imgw column (32 KB, coalesced float4)
  {
    const float4* wsrc = (const float4*)(imgw + (r * 12 + ec) * 4096);
    float4* wdst = (float4*)w_sh;
    #pragma unroll
    for (int j = 0; j < 8; ++j) wdst[t + j * 256] = wsrc[t + j * 256];
  }
  // stage ex slice: [k=0..32][pl=0..47]
  {
    const float2* esrc = ex2 + r * (33 * 96) + ps * 48;
    for (int idx = t; idx < 33 * 48; idx += 256) {
      int k = idx / 48, pl = idx - k * 48;
      ex_sh[idx] = esrc[k * 96 + pl];
    }
  }
  __syncthreads();

  // conjugate fold of w, in place. Rows 0 and 32 stay untouched (k = 1..31).
  float2 wa[8], wb[8];
  #pragma unroll
  for (int j = 0; j < 8; ++j) {
    int idx = t + j * 256;             // active < 1984 = 31*64
    if (idx < 1984) {
      int k = 1 + (idx >> 6), y = idx & 63;
      wa[j] = w_sh[(32 + k) * 64 + y];
      wb[j] = w_sh[(32 - k) * 64 + y];
    }
  }
  __syncthreads();
  #pragma unroll
  for (int j = 0; j < 8; ++j) {
    int idx = t + j * 256;
    if (idx < 1984) {
      int k = 1 + (idx >> 6), y = idx & 63;
      w_sh[(32 + k) * 64 + y] = make_float2(wa[j].x + wb[j].x, wa[j].y + wb[j].y);
      w_sh[(32 - k) * 64 + y] = make_float2(-(wa[j].y - wb[j].y), wa[j].x - wb[j].x);
    }
  }
  __syncthreads();

  // seed: acc[pp] = w[32] + w[0] * e^{+32i w0(p)}   (k=0 slot of ex_sh)
  v2f acc[12];
  {
    float2 w0v = w_sh[lane];
    float2 w32 = w_sh[32 * 64 + lane];
    #pragma unroll
    for (int pp = 0; pp < 12; ++pp) {
      float2 e0 = ex_sh[p0l + pp];
      acc[pp].x = w32.x + w0v.x * e0.x - w0v.y * e0.y;
      acc[pp].y = w32.y + w0v.x * e0.y + w0v.y * e0.x;
    }
  }

  #pragma unroll 2
  for (int k = 1; k < 32; ++k) {
    v2f sxy = *(const v2f*)&w_sh[(32 + k) * 64 + lane];
    v2f dyx = *(const v2f*)&w_sh[(32 - k) * 64 + lane];
    const float2* ekb = &ex_sh[k * 48 + p0l];
    #pragma unroll
    for (int pp = 0; pp < 12; ++pp) {
      float2 ev = ekb[pp];             // broadcast ds_read (lane-uniform)
      acc[pp] = __builtin_elementwise_fma(sxy, (v2f)(ev.x), acc[pp]);
      acc[pp] = __builtin_elementwise_fma(dyx, (v2f)(ev.y), acc[pp]);
    }
  }

  // epilogue: * ey(p, lane), reduce over lanes, store
  const float yy = (float)(lane - 32);
  #pragma unroll
  for (int pp = 0; pp < 12; ++pp) {
    const int p = p0 + pp;
    float w1 = kt[(r * 96 + p) * 2 + 1];
    float es, ecos;
    __sincosf(-w1 * yy, &es, &ecos);
    float vr = acc[pp].x * ecos - acc[pp].y * es;
    float vi = acc[pp].x * es  + acc[pp].y * ecos;
    #pragma unroll
    for (int off = 32; off; off >>= 1) {
      vr += __shfl_xor(vr, off);
      vi += __shfl_xor(vi, off);
    }
    if (lane == 0) out[((p * 4 + c) * 32 + r) * 3 + e] = make_float2(vr, vi);
  }
}

// ---------------------------------------------------------------------------
extern "C" void kernel_launch(void* const* d_in, const int* in_sizes, int n_in,
                              void* d_out, int out_size, void* d_ws, size_t ws_size,
                              hipStream_t stream) {
  const float2* sing  = (const float2*)d_in[0];
  const float2* smap  = (const float2*)d_in[1];
  const float*  ktraj = (const float*)d_in[2];
  const float*  ur    = (const float*)d_in[3];
  const int*    zbin  = (const int*)d_in[4];
  // d_in[5] = dc, unused in forward

  float2* ex2  = (float2*)d_ws;          // 811 KB
  float2* imgw = ex2 + EXG2_F2;          // 12.6 MB
  float2* out  = (float2*)d_out;

  precompute_imgw<<<NPIX / 4, 256, 0, stream>>>(sing, smap, ur, zbin, ktraj, ex2, imgw);
  nufft_points<<<NRO * NEC * 2, 256, 0, stream>>>(ktraj, ex2, imgw, out);
}